// Round 5
// baseline (14546.013 us; speedup 1.0000x reference)
//
#include <hip/hip_runtime.h>
#include <math.h>

// LSTM T=512, B=64, H=1024, L=2 — persistent-kernel version.
// 256 WGs x 512 threads, all co-resident. Each WG owns (layer, colgroup of 8
// hidden cols x all 4 gates x full K=2048); its W slice (128KB fp16) lives in
// REGISTERS (16 frags x 4 VGPR = 64 VGPR/lane) for the whole sequence.
// Diagonal schedule; one global barrier per diagonal step (monotonic atomic
// counter + device-scope fences for cross-XCD L2 coherence).
// Cell state c stays in one register per thread across all 512 steps.

#define T_STEPS 512
#define HID     1024
#define STATE   65536        // 64*1024
#define G4      4096
#define NWG     256
#define NCG     128          // col-groups of 8 per layer

typedef _Float16 f16;
typedef _Float16 f16x8 __attribute__((ext_vector_type(8)));
typedef float    f32x4 __attribute__((ext_vector_type(4)));

__device__ __forceinline__ float sigf(float x) { return 1.0f / (1.0f + __expf(-x)); }

// ---------------------------------------------------------------------------
// Pack W [2][2048][4096] f32 -> fp16 B-frags, frag id f = ((l*128+cg)*64+ks)*2+nf.
// Lane holds B[k = ks*32 + (lane>>4)*8 + j][n = g*1024 + cg*8 + c], j=0..7,
// where s = lane&15, g = nf*2 + (s>>3), c = s&7.  (frag slot s = 2 gates x 8 cols)
// ---------------------------------------------------------------------------
__global__ __launch_bounds__(256) void pack_w(const float* __restrict__ W,
                                              f16* __restrict__ pw)
{
    const size_t gt = (size_t)blockIdx.x * 256 + threadIdx.x;  // 2,097,152 threads
    const int lane = gt & 63;
    const size_t f = gt >> 6;                 // 0..32767
    const int nf = (int)(f & 1);
    const int ks = (int)((f >> 1) & 63);
    const int cg = (int)((f >> 7) & (NCG - 1));
    const int l  = (int)(f >> 14);
    const int s  = lane & 15;
    const int g  = nf * 2 + (s >> 3);
    const int c  = s & 7;
    const int k  = ks * 32 + ((lane >> 4) << 3);
    const int n  = g * HID + cg * 8 + c;
    const float* src = W + ((size_t)l * 2048 + k) * G4 + n;
    f16x8 v;
    #pragma unroll
    for (int j = 0; j < 8; ++j) v[j] = (f16)src[(size_t)j * G4];
    *(f16x8*)(pw + gt * 8) = v;
}

__global__ __launch_bounds__(256) void cvt_x0(const float* __restrict__ x,
                                              f16* __restrict__ xf)
{
    const int i = blockIdx.x * 256 + threadIdx.x;   // 65536
    xf[i] = (f16)x[i];
}

// Monotonic grid barrier: generation g complete when counter reaches g*NWG.
__device__ __forceinline__ void gbar(unsigned* bar, unsigned target)
{
    __syncthreads();                      // all waves: vmcnt(0) before barrier
    if (threadIdx.x == 0) {
        __threadfence();                  // release: L2 writeback (cross-XCD)
        __hip_atomic_fetch_add(bar, 1u, __ATOMIC_RELAXED, __HIP_MEMORY_SCOPE_AGENT);
        while (__hip_atomic_load(bar, __ATOMIC_RELAXED, __HIP_MEMORY_SCOPE_AGENT) < target)
            __builtin_amdgcn_s_sleep(4);
        __threadfence();                  // acquire: L2 invalidate
    }
    __syncthreads();
}

__global__ __launch_bounds__(512, 2) void lstm_persist(
    const f16* __restrict__ pw, const float* __restrict__ bias,
    const float* __restrict__ x,
    f16* xf0, f16* xf1,
    f16* h0a, f16* h0b, f16* h1a, f16* h1b,
    unsigned* bar, float* out)
{
    const int wgid  = blockIdx.x;          // 0..255
    const int layer = wgid >> 7;
    const int cg    = wgid & (NCG - 1);
    const int tid   = threadIdx.x;
    const int w     = tid >> 6;            // wave 0..7 (k-span w*256..+256)
    const int lane  = tid & 63;

    __shared__ __align__(16) float red[8][32][68];  // [wave][slot][row(+pad)]

    // ---- W slice -> registers (once) ----
    f16x8 wf[8][2];
    {
        const f16* base = pw + ((((size_t)layer * NCG + cg) * 64 + w * 8) * 2) * 512
                             + lane * 8;
        #pragma unroll
        for (int q = 0; q < 8; ++q)
            #pragma unroll
            for (int nf = 0; nf < 2; ++nf)
                wf[q][nf] = *(const f16x8*)(base + (q * 2 + nf) * 512);
    }

    // cell-phase mapping: thread -> (batch row, col within group)
    const int crow = tid >> 3;             // 0..63
    const int ccol = tid & 7;              // 0..7
    float bgate[4];
    #pragma unroll
    for (int g = 0; g < 4; ++g) bgate[g] = bias[layer * G4 + g * HID + cg * 8 + ccol];
    float creg = 0.0f;                     // cell state, lives here all 512 steps

    // A-frag addressing
    const int am    = lane & 15;
    const int ak    = (lane >> 4) << 3;    // 0,8,16,24
    const int kbase = (w & 3) * 256;

    float* dst = out + (size_t)T_STEPS * STATE;   // h_n, then c_n

    for (int d = 0; d <= T_STEPS; ++d) {
        const int act = layer ? (d >= 1) : (d < T_STEPS);
        const f16* xf_cur  = (d & 1) ? xf1 : xf0;   // x[d]
        const f16* h0_prev = (d & 1) ? h0a : h0b;   // h0 written at d-1
        const f16* h1_prev = (d & 1) ? h1a : h1b;   // h1 written at d-1
        f16* h0_new = (d & 1) ? h0b : h0a;
        f16* h1_new = (d & 1) ? h1b : h1a;

        if (act) {
            const f16* Ab = (layer == 0) ? ((w < 4) ? xf_cur  : h0_prev)
                                         : ((w < 4) ? h0_prev : h1_prev);
            f32x4 acc[4][2] = {};
            #pragma unroll
            for (int q = 0; q < 8; ++q) {
                const int kk = kbase + q * 32 + ak;
                f16x8 a[4];
                #pragma unroll
                for (int m = 0; m < 4; ++m)
                    a[m] = *(const f16x8*)(Ab + (size_t)(m * 16 + am) * HID + kk);
                #pragma unroll
                for (int m = 0; m < 4; ++m) {
                    acc[m][0] = __builtin_amdgcn_mfma_f32_16x16x32_f16(
                        a[m], wf[q][0], acc[m][0], 0, 0, 0);
                    acc[m][1] = __builtin_amdgcn_mfma_f32_16x16x32_f16(
                        a[m], wf[q][1], acc[m][1], 0, 0, 0);
                }
            }
            // C/D: slot = lane&15, row = m*16 + (lane>>4)*4 + r  (b128 stores)
            const int srow = (lane >> 4) * 4;
            const int slot = lane & 15;
            #pragma unroll
            for (int m = 0; m < 4; ++m) {
                *(f32x4*)&red[w][slot]     [m * 16 + srow] = acc[m][0];
                *(f32x4*)&red[w][16 + slot][m * 16 + srow] = acc[m][1];
            }
        }
        __syncthreads();

        if (act) {
            float gate[4];
            #pragma unroll
            for (int g = 0; g < 4; ++g) {
                float s = bgate[g];
                #pragma unroll
                for (int wv = 0; wv < 8; ++wv) s += red[wv][g * 8 + ccol][crow];
                gate[g] = s;
            }
            const float fg = sigf(gate[0]);
            const float ig = sigf(gate[1]);
            const float gg = tanhf(gate[2]);
            const float og = sigf(gate[3]);
            creg = fg * creg + ig * gg;
            const float hn = og * tanhf(creg);
            const int e = crow * HID + cg * 8 + ccol;
            if (layer) {
                h1_new[e] = (f16)hn;
                out[(size_t)(d - 1) * STATE + e] = hn;      // sequence output
                if (d == T_STEPS) dst[STATE + e] = hn;      // h_n[1]
            } else {
                h0_new[e] = (f16)hn;
                if (d == T_STEPS - 1) dst[e] = hn;          // h_n[0]
            }
        }

        // convert x[d+1] for next step (visible after the barrier)
        if (d + 1 < T_STEPS && tid < 256) {
            const int idx = wgid * 256 + tid;
            f16* xd = ((d + 1) & 1) ? xf1 : xf0;
            xd[idx] = (f16)x[(size_t)(d + 1) * STATE + idx];
        }

        if (d < T_STEPS) gbar(bar, (unsigned)(d + 1) * NWG);
    }

    // c_n (register-resident cell state)
    dst[2 * STATE + (size_t)layer * STATE + crow * HID + cg * 8 + ccol] = creg;
}

extern "C" void kernel_launch(void* const* d_in, const int* in_sizes, int n_in,
                              void* d_out, int out_size, void* d_ws, size_t ws_size,
                              hipStream_t stream)
{
    const float* x    = (const float*)d_in[0];
    const float* W    = (const float*)d_in[1];
    const float* bias = (const float*)d_in[2];
    float* out = (float*)d_out;

    f16* pw  = (f16*)d_ws;                              // 16,777,216 f16 = 32MB
    f16* xf0 = pw + (size_t)2 * NCG * 64 * 2 * 512;
    f16* xf1 = xf0 + STATE;
    f16* h0a = xf1 + STATE;
    f16* h0b = h0a + STATE;
    f16* h1a = h0b + STATE;
    f16* h1b = h1a + STATE;
    unsigned* bar = (unsigned*)(h1b + STATE);

    // zero x/h buffers + barrier counter (d_ws is re-poisoned every call)
    hipMemsetAsync(xf0, 0, (size_t)6 * STATE * sizeof(f16) + 256, stream);
    pack_w<<<8192, 256, 0, stream>>>(W, pw);
    cvt_x0<<<STATE / 256, 256, 0, stream>>>(x, xf0);

    lstm_persist<<<NWG, 512, 0, stream>>>(pw, bias, x, xf0, xf1,
                                          h0a, h0b, h1a, h1b, bar, out);
}